// Round 9
// baseline (8321.397 us; speedup 1.0000x reference)
//
#include <hip/hip_runtime.h>

// VQ-VAE quantization: N=32768, K=4096, D=256, fp32.
// Outputs (concat float32): z_q [N*D], idx [N] (as float), one_hot [N*K].
//
// Round-15: 2-plane pass + exact fixup, in the register-proven r12 shell.
// r14 failed on register pressure (96-reg second-min tracking -> spills,
// VALUBusy 58%). Here: same BM=64/512-block/u=4 structure as r12 (116-VGPR
// class), l-plane dropped from the sweep (products hh,hm,mh,mm = prefix of
// r12's chain; B-bytes 6.29->4.19 MB/block), and ambiguity tracked as a 1-BIT
// per-slot flag (sound over-approx of gap<=THR under pairwise merge).
// Flagged rows (expect ~1-2%) get exact 6-product recompute (vq_fixa, r12-
// bit-identical) + output rewrite (vq_fixb). THR=0.125 ~ 8x the |d4-d6| bound.

#define N_TOK 32768
#define K_CODE 4096
#define D_DIM 256
#define BM 64
#define THR_AMBIG 0.125f

typedef float f32x4 __attribute__((ext_vector_type(4)));
typedef short s16x8 __attribute__((ext_vector_type(8)));

// scratch in out[] tail (floats): escr ushort[3*K*D] (=1,572,864 f), e2[K],
// list int[32768], amin u64[32768] (=65,536 f), cnt pad[64].
#define OUT_FLOATS 142639104u          // N*D + N + N*K
#define EFRAG_SHORTS (3u * K_CODE * D_DIM)
#define SCR_FLOATS (EFRAG_SHORTS / 2 + K_CODE + 32768u + 65536u + 64u) // 1,675,328
#define SCR_OFF    (OUT_FLOATS - SCR_FLOATS)         // starts in one_hot row 32359
#define E2_OFF     (SCR_OFF + EFRAG_SHORTS / 2)
#define LIST_OFF   (E2_OFF + K_CODE)
#define AMIN_OFF   (LIST_OFF + 32768u)
#define CNT_OFF    (AMIN_OFF + 65536u)
#define OH_SAFE_ROWS 32320             // rows >= this: one_hot deferred to vq_oh_tail

#define MFMA(a, b, c) __builtin_amdgcn_mfma_f32_16x16x32_bf16((a), (b), (c), 0, 0, 0)

static __device__ __forceinline__ unsigned short f2bf(float f) {
    unsigned int u = __float_as_uint(f);
    u = (u + 0x7fffu + ((u >> 16) & 1u)) >> 16;
    return (unsigned short)u;
}
static __device__ __forceinline__ float bf2f(unsigned short b) {
    return __uint_as_float(((unsigned int)b) << 16);
}
static __device__ __forceinline__ unsigned long long packvi(float v, int code) {
    unsigned int u = __float_as_uint(v);
    u = (u & 0x80000000u) ? ~u : (u ^ 0x80000000u);   // order-preserving map
    return ((unsigned long long)u << 32) | (unsigned int)code;
}

// ---------------------------------------------------------------------------
// Prep: embed -> fragment-ordered bf16 h/m/l planes + e2; init list/amin/cnt.
// Frag layout (1KB): [ct_g(256)][dc(8)][c(3)][lane(64)][8 bf16].
// ---------------------------------------------------------------------------
__global__ __launch_bounds__(256) void vq_prep(const float* __restrict__ embed,
                                               float* __restrict__ out) {
    __shared__ float part[8][33];
    unsigned short* escr = (unsigned short*)(out + SCR_OFF);
    float* e2g = out + E2_OFF;

    const int t    = threadIdx.x;
    const int cl   = t >> 5;
    const int r32  = t & 31;
    const int dc   = r32 >> 2;
    const int quad = r32 & 3;
    const int k    = blockIdx.x * 8 + cl;

    if (blockIdx.x == 0) {                      // re-init fixup state every launch
        if (t == 0) ((int*)(out + CNT_OFF))[0] = 0;
        unsigned long long* am = (unsigned long long*)(out + AMIN_OFF);
        for (int i = t; i < 32768; i += 256) am[i] = ~0ull;
    }

    const float* src = embed + (size_t)k * D_DIM + dc * 32 + quad * 8;
    float x[8];
    *(float4*)(x)     = *(const float4*)(src);
    *(float4*)(x + 4) = *(const float4*)(src + 4);

    s16x8 hv, mv, lv;
    float s2 = 0.0f;
#pragma unroll
    for (int j = 0; j < 8; ++j) {
        const float xx = x[j];
        s2 += xx * xx;
        const unsigned short bh = f2bf(xx);
        const float r1 = xx - bf2f(bh);
        const unsigned short bm = f2bf(r1);
        hv[j] = (short)bh; mv[j] = (short)bm; lv[j] = (short)f2bf(r1 - bf2f(bm));
    }

    const int ct_g = k >> 4;
    const int lane = quad * 16 + (k & 15);
    const size_t base = ((size_t)(ct_g * 8 + dc) * 3) * 512 + lane * 8;
    *(s16x8*)&escr[base]        = hv;
    *(s16x8*)&escr[base + 512]  = mv;
    *(s16x8*)&escr[base + 1024] = lv;

    part[cl][r32] = s2;
    __syncthreads();
    if (t < 8) {
        float s = 0.0f;
#pragma unroll
        for (int j = 0; j < 32; ++j) s += part[t][j];   // fixed order: deterministic
        e2g[blockIdx.x * 8 + t] = s;
    }
}

// ---- helpers (2-plane main loop) ------------------------------------------
static __device__ __forceinline__ void load_b2(const unsigned short* __restrict__ p,
                                               s16x8 (&buf)[4][2]) {
#pragma unroll
    for (int u = 0; u < 4; ++u)
#pragma unroll
        for (int c = 0; c < 2; ++c)
            buf[u][c] = *(const s16x8*)(p + u * 12288 + c * 512);
}

static __device__ __forceinline__ size_t boff(int s) {
    return (size_t)(s >> 3) * 393216 + (size_t)(s & 7) * 1536;
}

static __device__ __forceinline__ void proc2(const short* As,
        const float* __restrict__ e2g, int s, int wu, int lane, int n,
        s16x8 (&B)[4][2], f32x4 (&acc)[4][4], float (&e2r)[4],
        float (&bv)[16], int (&bidx)[16], unsigned int& amb) {
    const int ktp = s >> 3;
    const int dc  = s & 7;
    if (dc == 0) {       // prefetch e2 8 steps ahead of its dc==7 use
#pragma unroll
        for (int u = 0; u < 4; ++u)
            e2r[u] = e2g[ktp * 512 + (wu * 4 + u) * 16 + n];
    }
#pragma unroll
    for (int rt = 0; rt < 4; ++rt) {
        s16x8 af0 = *(const s16x8*)&As[((0 * 4 + rt) * 8 + dc) * 512 + lane * 8];
        s16x8 af1 = *(const s16x8*)&As[((1 * 4 + rt) * 8 + dc) * 512 + lane * 8];
#pragma unroll
        for (int u = 0; u < 4; ++u) {
            f32x4 a = acc[rt][u];
            a = MFMA(af0, B[u][0], a);           // hh
            a = MFMA(af0, B[u][1], a);           // hm
            a = MFMA(af1, B[u][0], a);           // mh
            a = MFMA(af1, B[u][1], a);           // mm  (prefix of r12's 6-chain)
            acc[rt][u] = a;
        }
    }
    if (dc == 7) {   // merge with 1-bit ambiguity flag per slot
#pragma unroll
        for (int u = 0; u < 4; ++u) {
            const int code = ktp * 512 + (wu * 4 + u) * 16 + n;
#pragma unroll
            for (int rt = 0; rt < 4; ++rt)
#pragma unroll
                for (int r = 0; r < 4; ++r) {
                    const float val = fmaf(-2.0f, acc[rt][u][r], e2r[u]);
                    const int slot = rt * 4 + r;
                    if (val < bv[slot] || (val == bv[slot] && code < bidx[slot])) {
                        if (bv[slot] - val <= THR_AMBIG) amb |= (1u << slot);
                        bv[slot] = val; bidx[slot] = code;
                    } else if (val - bv[slot] <= THR_AMBIG) {
                        amb |= (1u << slot);
                    }
                }
        }
#pragma unroll
        for (int rt = 0; rt < 4; ++rt)
#pragma unroll
            for (int u = 0; u < 4; ++u) acc[rt][u] = (f32x4){0.f, 0.f, 0.f, 0.f};
    }
}

// ---------------------------------------------------------------------------
// Pass 1 (2-plane): 512 thr = 8 waves, 64 rows/block, grid 512 (2 rounds).
// LDS = A h,m only (64KB). 64-step (ktp,dc) loop, u=4/wave, ping-pong B.
// Ambiguous rows -> global list; outputs written with pass-1 winner (fixb
// corrects the few changed rows afterwards).
// ---------------------------------------------------------------------------
__global__ __launch_bounds__(512, 2)
void vq_pass1(const float* __restrict__ z_e,
              const float* __restrict__ embed,
              float* __restrict__ out) {
    __shared__ __align__(16) short As[32768];   // [(c*4+rt)*8+dc]*512 + ls*8, c in {h,m}
    __shared__ float redv[64][9];
    __shared__ int   redi[64][9];
    __shared__ int   reda[64][9];
    __shared__ int   bk_lds[64];

    const unsigned short* escr = (const unsigned short*)(out + SCR_OFF);
    const float* e2g = out + E2_OFF;
    int* list = (int*)(out + LIST_OFF);
    int* cnt  = (int*)(out + CNT_OFF);

    const int t    = threadIdx.x;
    const int w    = t >> 6;
    const int lane = t & 63;
    const int n    = lane & 15;
    const int quad = lane >> 4;
    const int row0 = blockIdx.x * BM;

    // ---- stage + convert A (h,m planes) ----
#pragma unroll
    for (int i = 0; i < 4; ++i) {
        const int run  = t + 512 * i;           // (row, dcs, qs): 64*8*4 = 2048
        const int qs   = run & 3;
        const int dcs  = (run >> 2) & 7;
        const int row  = run >> 5;
        const float* src = z_e + (size_t)(row0 + row) * D_DIM + dcs * 32 + qs * 8;
        float x[8];
        *(float4*)(x)     = *(const float4*)(src);
        *(float4*)(x + 4) = *(const float4*)(src + 4);
        s16x8 hv, mv;
#pragma unroll
        for (int j = 0; j < 8; ++j) {
            const float xx = x[j];
            const unsigned short bh = f2bf(xx);
            hv[j] = (short)bh;
            mv[j] = (short)f2bf(xx - bf2f(bh));
        }
        const int rt = row >> 4;
        const int ls = qs * 16 + (row & 15);
        *(s16x8*)&As[((0 * 4 + rt) * 8 + dcs) * 512 + ls * 8] = hv;
        *(s16x8*)&As[((1 * 4 + rt) * 8 + dcs) * 512 + ls * 8] = mv;
    }
    __syncthreads();

    float bv[16];
    int   bidx[16];
    unsigned int amb = 0u;
#pragma unroll
    for (int s = 0; s < 16; ++s) { bv[s] = 3.0e38f; bidx[s] = 0x7fffffff; }

    f32x4 acc[4][4];
#pragma unroll
    for (int rt = 0; rt < 4; ++rt)
#pragma unroll
        for (int u = 0; u < 4; ++u) acc[rt][u] = (f32x4){0.f, 0.f, 0.f, 0.f};

    float e2r[4];
    s16x8 b0[4][2], b1[4][2];

    const int wu = __builtin_amdgcn_readfirstlane(w);
    const unsigned short* ebase = escr + (size_t)wu * 49152 + lane * 8;

    load_b2(ebase, b0);                          // step 0

#pragma unroll 1
    for (int it = 0; it < 32; ++it) {
        const int s0 = it * 2, s1 = s0 + 1, s2 = s0 + 2;
        load_b2(ebase + boff(s1), b1);
        proc2(As, e2g, s0, wu, lane, n, b0, acc, e2r, bv, bidx, amb);
        if (it < 31) load_b2(ebase + boff(s2), b0);
        proc2(As, e2g, s1, wu, lane, n, b1, acc, e2r, bv, bidx, amb);
    }

    // butterfly over 16 lanes: lex (v,i) min + ambiguity propagation
#pragma unroll
    for (int mask = 1; mask < 16; mask <<= 1) {
        const unsigned int oamb = __shfl_xor((int)amb, mask);
        unsigned int close = 0u;
#pragma unroll
        for (int slot = 0; slot < 16; ++slot) {
            const float ov = __shfl_xor(bv[slot], mask);
            const int   oi = __shfl_xor(bidx[slot], mask);
            if (fabsf(ov - bv[slot]) <= THR_AMBIG) close |= (1u << slot);
            if (ov < bv[slot] || (ov == bv[slot] && oi < bidx[slot])) {
                bv[slot] = ov; bidx[slot] = oi;
            }
        }
        amb |= oamb | close;
    }
    if (n == 0) {
#pragma unroll
        for (int rt = 0; rt < 4; ++rt)
#pragma unroll
            for (int r = 0; r < 4; ++r) {
                const int rl = rt * 16 + quad * 4 + r;   // C/D: row=quad*4+reg
                const int slot = rt * 4 + r;
                redv[rl][w] = bv[slot];
                redi[rl][w] = bidx[slot];
                reda[rl][w] = (int)((amb >> slot) & 1u);
            }
    }
    __syncthreads();
    if (t < 64) {
        float v = redv[t][0];
        int  bi = redi[t][0];
        int  am = reda[t][0];
#pragma unroll
        for (int j = 1; j < 8; ++j) {
            const float v2 = redv[t][j];
            const int   i2 = redi[t][j];
            am |= reda[t][j] | (fabsf(v2 - v) <= THR_AMBIG ? 1 : 0);
            if (v2 < v || (v2 == v && i2 < bi)) { v = v2; bi = i2; }
        }
        bk_lds[t] = bi;
        out[(size_t)N_TOK * D_DIM + (size_t)(row0 + t)] = (float)bi;
        if (am) {
            const int pos = atomicAdd(cnt, 1);   // pos < N always (one per row)
            list[pos] = row0 + t;
        }
    }
    __syncthreads();

    // ---- fused output tail (fixb corrects flagged rows later) ----
    float* zq = out;
    float* oh = out + (size_t)N_TOK * D_DIM + N_TOK;

#pragma unroll 1
    for (int rr = 0; rr < 8; ++rr) {            // z_q: wave w owns rows w*8..w*8+7
        const int rl  = w * 8 + rr;
        const int row = row0 + rl;
        const int bk  = bk_lds[rl] & (K_CODE - 1);
        f32x4 v = *(const f32x4*)&embed[(size_t)bk * D_DIM + lane * 4];
        __builtin_nontemporal_store(v, (f32x4*)&zq[(size_t)row * D_DIM + lane * 4]);
    }
    if (row0 < OH_SAFE_ROWS) {                  // scratch-overlap rows deferred
#pragma unroll 1
        for (int rr = 0; rr < 8; ++rr) {
            const int rl  = w * 8 + rr;
            const int row = row0 + rl;
            const int bk  = bk_lds[rl];
            float* ohrow = &oh[(size_t)row * K_CODE];
#pragma unroll
            for (int g = 0; g < 16; ++g) {
                const int base = (g * 64 + lane) * 4;
                f32x4 u;
                u.x = (bk == base    ) ? 1.0f : 0.0f;
                u.y = (bk == base + 1) ? 1.0f : 0.0f;
                u.z = (bk == base + 2) ? 1.0f : 0.0f;
                u.w = (bk == base + 3) ? 1.0f : 0.0f;
                __builtin_nontemporal_store(u, (f32x4*)&ohrow[base]);
            }
        }
    }
}

// ---------------------------------------------------------------------------
// Fixup A: exact 6-product recompute for listed rows (bit-identical to r12's
// chain). Grid 16 = 8 code-slices x 2 chunk strides; each block gathers <=64
// rows, sweeps its 512-code slice, atomicMin's a lex-packed u64 per row.
// ---------------------------------------------------------------------------
__global__ __launch_bounds__(512, 2)
void vq_fixa(const float* __restrict__ z_e, float* __restrict__ out) {
    __shared__ __align__(16) short As[49152];   // 96KB, r12 3-plane layout
    __shared__ float redv[64][9];
    __shared__ int   redi[64][9];
    __shared__ int   rows_lds[64];

    const unsigned short* escr = (const unsigned short*)(out + SCR_OFF);
    const float* e2g = out + E2_OFF;
    const int* list = (const int*)(out + LIST_OFF);
    unsigned long long* amin = (unsigned long long*)(out + AMIN_OFF);
    const int cntv = ((const int*)(out + CNT_OFF))[0];
    const int ncap = cntv < N_TOK ? cntv : N_TOK;
    if (ncap <= 0) return;

    const int t    = threadIdx.x;
    const int w    = t >> 6;
    const int lane = t & 63;
    const int n    = lane & 15;
    const int quad = lane >> 4;
    const int slice = blockIdx.x & 7;            // ktp 0..7 (512 codes each)
    const int c0    = blockIdx.x >> 3;

    const int wu = __builtin_amdgcn_readfirstlane(w);
    const unsigned short* ebase = escr + (size_t)wu * 49152 + lane * 8;

#pragma unroll 1
    for (int chunk = c0; chunk * 64 < ncap; chunk += 2) {
        const int nrows = (ncap - chunk * 64) < 64 ? (ncap - chunk * 64) : 64;
        if (t < 64) {
            const int j = chunk * 64 + t;
            rows_lds[t] = list[j < ncap ? j : chunk * 64];   // pad = dup row
        }
        __syncthreads();

        // gather-stage + convert A (3 planes, 64 rows)
#pragma unroll
        for (int i = 0; i < 4; ++i) {
            const int run  = t + 512 * i;
            const int qs   = run & 3;
            const int dcs  = (run >> 2) & 7;
            const int row  = run >> 5;
            const int grow = rows_lds[row];
            const float* src = z_e + (size_t)grow * D_DIM + dcs * 32 + qs * 8;
            float x[8];
            *(float4*)(x)     = *(const float4*)(src);
            *(float4*)(x + 4) = *(const float4*)(src + 4);
            s16x8 hv, mv, lv;
#pragma unroll
            for (int j = 0; j < 8; ++j) {
                const float xx = x[j];
                const unsigned short bh = f2bf(xx);
                const float r1 = xx - bf2f(bh);
                const unsigned short bm = f2bf(r1);
                hv[j] = (short)bh; mv[j] = (short)bm; lv[j] = (short)f2bf(r1 - bf2f(bm));
            }
            const int rt = row >> 4;
            const int ls = qs * 16 + (row & 15);
            *(s16x8*)&As[((0 * 4 + rt) * 8 + dcs) * 512 + ls * 8] = hv;
            *(s16x8*)&As[((1 * 4 + rt) * 8 + dcs) * 512 + ls * 8] = mv;
            *(s16x8*)&As[((2 * 4 + rt) * 8 + dcs) * 512 + ls * 8] = lv;
        }
        __syncthreads();

        float bv[16]; int bidx[16];
#pragma unroll
        for (int s = 0; s < 16; ++s) { bv[s] = 3.0e38f; bidx[s] = 0x7fffffff; }
        f32x4 acc[4][4];
#pragma unroll
        for (int rt = 0; rt < 4; ++rt)
#pragma unroll
            for (int u = 0; u < 4; ++u) acc[rt][u] = (f32x4){0.f, 0.f, 0.f, 0.f};
        float e2r[4];

#pragma unroll 1
        for (int dc = 0; dc < 8; ++dc) {         // single-buffered: tiny sweep
            s16x8 B[4][3];
            const unsigned short* p = ebase + (size_t)slice * 393216 + (size_t)dc * 1536;
#pragma unroll
            for (int u = 0; u < 4; ++u)
#pragma unroll
                for (int c = 0; c < 3; ++c)
                    B[u][c] = *(const s16x8*)(p + u * 12288 + c * 512);
            if (dc == 0) {
#pragma unroll
                for (int u = 0; u < 4; ++u)
                    e2r[u] = e2g[slice * 512 + (wu * 4 + u) * 16 + n];
            }
#pragma unroll
            for (int rt = 0; rt < 4; ++rt) {
                s16x8 af0 = *(const s16x8*)&As[((0 * 4 + rt) * 8 + dc) * 512 + lane * 8];
                s16x8 af1 = *(const s16x8*)&As[((1 * 4 + rt) * 8 + dc) * 512 + lane * 8];
                s16x8 af2 = *(const s16x8*)&As[((2 * 4 + rt) * 8 + dc) * 512 + lane * 8];
#pragma unroll
                for (int u = 0; u < 4; ++u) {
                    f32x4 a = acc[rt][u];
                    a = MFMA(af0, B[u][0], a);   // hh
                    a = MFMA(af0, B[u][1], a);   // hm
                    a = MFMA(af1, B[u][0], a);   // mh
                    a = MFMA(af1, B[u][1], a);   // mm
                    a = MFMA(af0, B[u][2], a);   // hl
                    a = MFMA(af2, B[u][0], a);   // lh
                    acc[rt][u] = a;
                }
            }
        }
#pragma unroll
        for (int u = 0; u < 4; ++u) {
            const int code = slice * 512 + (wu * 4 + u) * 16 + n;
#pragma unroll
            for (int rt = 0; rt < 4; ++rt)
#pragma unroll
                for (int r = 0; r < 4; ++r) {
                    const float val = fmaf(-2.0f, acc[rt][u][r], e2r[u]);
                    const int slot = rt * 4 + r;
                    if (val < bv[slot] || (val == bv[slot] && code < bidx[slot])) {
                        bv[slot] = val; bidx[slot] = code;
                    }
                }
        }
#pragma unroll
        for (int slot = 0; slot < 16; ++slot) {
#pragma unroll
            for (int mask = 1; mask < 16; mask <<= 1) {
                const float ov = __shfl_xor(bv[slot], mask);
                const int   oi = __shfl_xor(bidx[slot], mask);
                if (ov < bv[slot] || (ov == bv[slot] && oi < bidx[slot])) {
                    bv[slot] = ov; bidx[slot] = oi;
                }
            }
        }
        if (n == 0) {
#pragma unroll
            for (int rt = 0; rt < 4; ++rt)
#pragma unroll
                for (int r = 0; r < 4; ++r) {
                    const int rl = rt * 16 + quad * 4 + r;
                    redv[rl][w] = bv[rt * 4 + r];
                    redi[rl][w] = bidx[rt * 4 + r];
                }
        }
        __syncthreads();
        if (t < nrows) {
            float v = redv[t][0]; int bi = redi[t][0];
#pragma unroll
            for (int j = 1; j < 8; ++j) {
                const float v2 = redv[t][j]; const int i2 = redi[t][j];
                if (v2 < v || (v2 == v && i2 < bi)) { v = v2; bi = i2; }
            }
            atomicMin(&amin[chunk * 64 + t], packvi(v, bi));
        }
        __syncthreads();
    }
}

// ---------------------------------------------------------------------------
// Fixup B: apply corrected winners (idx, z_q row, one_hot 2-entry flip).
// ---------------------------------------------------------------------------
__global__ __launch_bounds__(256) void vq_fixb(const float* __restrict__ embed,
                                               float* __restrict__ out) {
    const int* list = (const int*)(out + LIST_OFF);
    const unsigned long long* amin = (const unsigned long long*)(out + AMIN_OFF);
    const int cntv = ((const int*)(out + CNT_OFF))[0];
    const int ncap = cntv < N_TOK ? cntv : N_TOK;

    float* idxf = out + (size_t)N_TOK * D_DIM;
    float* zq   = out;
    float* oh   = out + (size_t)N_TOK * D_DIM + N_TOK;
    const int t = threadIdx.x;

#pragma unroll 1
    for (int e = blockIdx.x; e < ncap; e += 32) {
        const int row = list[e];
        const int bi  = (int)(amin[e] & 0xffffffffu) & (K_CODE - 1);
        const int io  = ((int)idxf[row]) & (K_CODE - 1);
        if (bi != io) {
            if (t == 0) idxf[row] = (float)bi;
            if (t < 64) {
                f32x4 v = *(const f32x4*)&embed[(size_t)bi * D_DIM + t * 4];
                *(f32x4*)&zq[(size_t)row * D_DIM + t * 4] = v;
            }
            if (row < OH_SAFE_ROWS && t == 0) {
                oh[(size_t)row * K_CODE + io] = 0.0f;
                oh[(size_t)row * K_CODE + bi] = 1.0f;
            }
        }
    }
}

// ---------------------------------------------------------------------------
// Cleanup: one_hot for rows 32320..32767 (scratch overlap region). Runs last,
// reads final (fixed) idx.
// ---------------------------------------------------------------------------
__launch_bounds__(256, 8)
__global__ void vq_oh_tail(float* __restrict__ out) {
    __shared__ int bks[16];
    const int t    = threadIdx.x;
    const int w    = t >> 6;
    const int lane = t & 63;
    const int row0 = OH_SAFE_ROWS + blockIdx.x * 16;

    const float* idxf = out + (size_t)N_TOK * D_DIM;
    float* oh = out + (size_t)N_TOK * D_DIM + N_TOK;

    if (t < 16) bks[t] = ((int)idxf[row0 + t]) & (K_CODE - 1);
    __syncthreads();

#pragma unroll 1
    for (int rr = 0; rr < 4; ++rr) {
        const int r   = rr * 4 + w;
        const int row = row0 + r;
        const int bk  = bks[r];
        float* ohrow = &oh[(size_t)row * K_CODE];
#pragma unroll
        for (int g = 0; g < 16; ++g) {
            const int base = (g * 64 + lane) * 4;
            f32x4 u;
            u.x = (bk == base    ) ? 1.0f : 0.0f;
            u.y = (bk == base + 1) ? 1.0f : 0.0f;
            u.z = (bk == base + 2) ? 1.0f : 0.0f;
            u.w = (bk == base + 3) ? 1.0f : 0.0f;
            __builtin_nontemporal_store(u, (f32x4*)&ohrow[base]);
        }
    }
}

extern "C" void kernel_launch(void* const* d_in, const int* in_sizes, int n_in,
                              void* d_out, int out_size, void* d_ws, size_t ws_size,
                              hipStream_t stream) {
    const float* z_e   = (const float*)d_in[0];
    const float* embed = (const float*)d_in[1];
    float* out = (float*)d_out;

    hipLaunchKernelGGL(vq_prep,    dim3(K_CODE / 8), dim3(256), 0, stream, embed, out);
    hipLaunchKernelGGL(vq_pass1,   dim3(N_TOK / BM), dim3(512), 0, stream, z_e, embed, out);
    hipLaunchKernelGGL(vq_fixa,    dim3(16),  dim3(512), 0, stream, z_e, out);
    hipLaunchKernelGGL(vq_fixb,    dim3(32),  dim3(256), 0, stream, embed, out);
    hipLaunchKernelGGL(vq_oh_tail, dim3((N_TOK - OH_SAFE_ROWS) / 16), dim3(256), 0, stream, out);
}

// Round 10
// 897.829 us; speedup vs baseline: 9.2684x; 9.2684x over previous
//
#include <hip/hip_runtime.h>

// VQ-VAE quantization: N=32768, K=4096, D=256, fp32.
// Outputs (concat float32): z_q [N*D], idx [N] (as float), one_hot [N*K].
//
// Round-16: 2-plane pass + exact fixup, with an EXACT runner-up (v2) instead
// of r15's 1-bit flag. r15's flag was a sound but wildly loose over-approx
// (near-record events vs the RUNNING min + 64 partial-minima comparisons per
// row => ~100% flag rate => fixa recomputed all N rows, 6.4ms). v2 tracking
// gives the true final gap test (rate ~2%). Register budget kept under the
// 128 cap by packing the argmin codes two-per-u32 (12-bit codes, compile-time
// slot indices). Ties => v2==v1 => flagged => exact fixup resolves lex order,
// so merges need no tie-break. Fixup path (vq_fixa/vq_fixb) is unchanged from
// r15, where it was validated end-to-end (recomputed rows matched reference).

#define N_TOK 32768
#define K_CODE 4096
#define D_DIM 256
#define BM 64
#define THR_AMBIG 0.125f

typedef float f32x4 __attribute__((ext_vector_type(4)));
typedef short s16x8 __attribute__((ext_vector_type(8)));

// scratch in out[] tail (floats): escr ushort[3*K*D] (=1,572,864 f), e2[K],
// list int[32768], amin u64[32768] (=65,536 f), cnt pad[64].
#define OUT_FLOATS 142639104u          // N*D + N + N*K
#define EFRAG_SHORTS (3u * K_CODE * D_DIM)
#define SCR_FLOATS (EFRAG_SHORTS / 2 + K_CODE + 32768u + 65536u + 64u) // 1,675,328
#define SCR_OFF    (OUT_FLOATS - SCR_FLOATS)         // starts in one_hot row 32359
#define E2_OFF     (SCR_OFF + EFRAG_SHORTS / 2)
#define LIST_OFF   (E2_OFF + K_CODE)
#define AMIN_OFF   (LIST_OFF + 32768u)
#define CNT_OFF    (AMIN_OFF + 65536u)
#define OH_SAFE_ROWS 32320             // rows >= this: one_hot deferred to vq_oh_tail

#define MFMA(a, b, c) __builtin_amdgcn_mfma_f32_16x16x32_bf16((a), (b), (c), 0, 0, 0)

static __device__ __forceinline__ unsigned short f2bf(float f) {
    unsigned int u = __float_as_uint(f);
    u = (u + 0x7fffu + ((u >> 16) & 1u)) >> 16;
    return (unsigned short)u;
}
static __device__ __forceinline__ float bf2f(unsigned short b) {
    return __uint_as_float(((unsigned int)b) << 16);
}
static __device__ __forceinline__ unsigned long long packvi(float v, int code) {
    unsigned int u = __float_as_uint(v);
    u = (u & 0x80000000u) ? ~u : (u ^ 0x80000000u);   // order-preserving map
    return ((unsigned long long)u << 32) | (unsigned int)code;
}

// ---------------------------------------------------------------------------
// Prep: embed -> fragment-ordered bf16 h/m/l planes + e2; init list/amin/cnt.
// Frag layout (1KB): [ct_g(256)][dc(8)][c(3)][lane(64)][8 bf16].
// ---------------------------------------------------------------------------
__global__ __launch_bounds__(256) void vq_prep(const float* __restrict__ embed,
                                               float* __restrict__ out) {
    __shared__ float part[8][33];
    unsigned short* escr = (unsigned short*)(out + SCR_OFF);
    float* e2g = out + E2_OFF;

    const int t    = threadIdx.x;
    const int cl   = t >> 5;
    const int r32  = t & 31;
    const int dc   = r32 >> 2;
    const int quad = r32 & 3;
    const int k    = blockIdx.x * 8 + cl;

    if (blockIdx.x == 0) {                      // re-init fixup state every launch
        if (t == 0) ((int*)(out + CNT_OFF))[0] = 0;
        unsigned long long* am = (unsigned long long*)(out + AMIN_OFF);
        for (int i = t; i < 32768; i += 256) am[i] = ~0ull;
    }

    const float* src = embed + (size_t)k * D_DIM + dc * 32 + quad * 8;
    float x[8];
    *(float4*)(x)     = *(const float4*)(src);
    *(float4*)(x + 4) = *(const float4*)(src + 4);

    s16x8 hv, mv, lv;
    float s2 = 0.0f;
#pragma unroll
    for (int j = 0; j < 8; ++j) {
        const float xx = x[j];
        s2 += xx * xx;
        const unsigned short bh = f2bf(xx);
        const float r1 = xx - bf2f(bh);
        const unsigned short bm = f2bf(r1);
        hv[j] = (short)bh; mv[j] = (short)bm; lv[j] = (short)f2bf(r1 - bf2f(bm));
    }

    const int ct_g = k >> 4;
    const int lane = quad * 16 + (k & 15);
    const size_t base = ((size_t)(ct_g * 8 + dc) * 3) * 512 + lane * 8;
    *(s16x8*)&escr[base]        = hv;
    *(s16x8*)&escr[base + 512]  = mv;
    *(s16x8*)&escr[base + 1024] = lv;

    part[cl][r32] = s2;
    __syncthreads();
    if (t < 8) {
        float s = 0.0f;
#pragma unroll
        for (int j = 0; j < 32; ++j) s += part[t][j];   // fixed order: deterministic
        e2g[blockIdx.x * 8 + t] = s;
    }
}

// ---- helpers (2-plane main loop) ------------------------------------------
static __device__ __forceinline__ void load_b2(const unsigned short* __restrict__ p,
                                               s16x8 (&buf)[4][2]) {
#pragma unroll
    for (int u = 0; u < 4; ++u)
#pragma unroll
        for (int c = 0; c < 2; ++c)
            buf[u][c] = *(const s16x8*)(p + u * 12288 + c * 512);
}

static __device__ __forceinline__ size_t boff(int s) {
    return (size_t)(s >> 3) * 393216 + (size_t)(s & 7) * 1536;
}

static __device__ __forceinline__ void proc2(const short* As,
        const float* __restrict__ e2g, int s, int wu, int lane, int n,
        s16x8 (&B)[4][2], f32x4 (&acc)[4][4], float (&e2r)[4],
        float (&bv)[16], float (&bv2)[16], unsigned int (&pk)[8]) {
    const int ktp = s >> 3;
    const int dc  = s & 7;
    if (dc == 0) {       // prefetch e2 8 steps ahead of its dc==7 use
#pragma unroll
        for (int u = 0; u < 4; ++u)
            e2r[u] = e2g[ktp * 512 + (wu * 4 + u) * 16 + n];
    }
#pragma unroll
    for (int rt = 0; rt < 4; ++rt) {
        s16x8 af0 = *(const s16x8*)&As[((0 * 4 + rt) * 8 + dc) * 512 + lane * 8];
        s16x8 af1 = *(const s16x8*)&As[((1 * 4 + rt) * 8 + dc) * 512 + lane * 8];
#pragma unroll
        for (int u = 0; u < 4; ++u) {
            f32x4 a = acc[rt][u];
            a = MFMA(af0, B[u][0], a);           // hh
            a = MFMA(af0, B[u][1], a);           // hm
            a = MFMA(af1, B[u][0], a);           // mh
            a = MFMA(af1, B[u][1], a);           // mm  (prefix of r12's 6-chain)
            acc[rt][u] = a;
        }
    }
    if (dc == 7) {   // merge: (v1, v2) exact; codes ascend => first-occurrence
#pragma unroll
        for (int u = 0; u < 4; ++u) {
            const int code = ktp * 512 + (wu * 4 + u) * 16 + n;
#pragma unroll
            for (int rt = 0; rt < 4; ++rt)
#pragma unroll
                for (int r = 0; r < 4; ++r) {
                    const float val = fmaf(-2.0f, acc[rt][u][r], e2r[u]);
                    const int slot = rt * 4 + r;
                    const int k = slot >> 1, sh = (slot & 1) * 16;
                    if (val < bv[slot]) {
                        bv2[slot] = bv[slot];
                        bv[slot] = val;
                        pk[k] = (pk[k] & ~(0xFFFFu << sh)) | ((unsigned int)code << sh);
                    } else {
                        bv2[slot] = fminf(bv2[slot], val);
                    }
                }
        }
#pragma unroll
        for (int rt = 0; rt < 4; ++rt)
#pragma unroll
            for (int u = 0; u < 4; ++u) acc[rt][u] = (f32x4){0.f, 0.f, 0.f, 0.f};
    }
}

// ---------------------------------------------------------------------------
// Pass 1 (2-plane): 512 thr = 8 waves, 64 rows/block, grid 512. LDS = A h,m
// (64KB). 64-step (ktp,dc) loop, u=4/wave, ping-pong B. Per-slot (v1, v2,
// packed code); flag = final gap <= THR. Flagged rows -> list; outputs get the
// pass-1 winner (fixb corrects the few changed rows afterwards).
// ---------------------------------------------------------------------------
__global__ __launch_bounds__(512, 2)
void vq_pass1(const float* __restrict__ z_e,
              const float* __restrict__ embed,
              float* __restrict__ out) {
    __shared__ __align__(16) short As[32768];   // [(c*4+rt)*8+dc]*512 + ls*8, c in {h,m}
    __shared__ float redv1[64][9];
    __shared__ float redv2[64][9];
    __shared__ int   redi[64][9];
    __shared__ int   bk_lds[64];

    const unsigned short* escr = (const unsigned short*)(out + SCR_OFF);
    const float* e2g = out + E2_OFF;
    int* list = (int*)(out + LIST_OFF);
    int* cnt  = (int*)(out + CNT_OFF);

    const int t    = threadIdx.x;
    const int w    = t >> 6;
    const int lane = t & 63;
    const int n    = lane & 15;
    const int quad = lane >> 4;
    const int row0 = blockIdx.x * BM;

    // ---- stage + convert A (h,m planes) ----
#pragma unroll
    for (int i = 0; i < 4; ++i) {
        const int run  = t + 512 * i;           // (row, dcs, qs): 64*8*4 = 2048
        const int qs   = run & 3;
        const int dcs  = (run >> 2) & 7;
        const int row  = run >> 5;
        const float* src = z_e + (size_t)(row0 + row) * D_DIM + dcs * 32 + qs * 8;
        float x[8];
        *(float4*)(x)     = *(const float4*)(src);
        *(float4*)(x + 4) = *(const float4*)(src + 4);
        s16x8 hv, mv;
#pragma unroll
        for (int j = 0; j < 8; ++j) {
            const float xx = x[j];
            const unsigned short bh = f2bf(xx);
            hv[j] = (short)bh;
            mv[j] = (short)f2bf(xx - bf2f(bh));
        }
        const int rt = row >> 4;
        const int ls = qs * 16 + (row & 15);
        *(s16x8*)&As[((0 * 4 + rt) * 8 + dcs) * 512 + ls * 8] = hv;
        *(s16x8*)&As[((1 * 4 + rt) * 8 + dcs) * 512 + ls * 8] = mv;
    }
    __syncthreads();

    float bv[16], bv2[16];
    unsigned int pk[8];
#pragma unroll
    for (int s = 0; s < 16; ++s) { bv[s] = 3.0e38f; bv2[s] = 3.0e38f; }
#pragma unroll
    for (int k = 0; k < 8; ++k) pk[k] = 0u;

    f32x4 acc[4][4];
#pragma unroll
    for (int rt = 0; rt < 4; ++rt)
#pragma unroll
        for (int u = 0; u < 4; ++u) acc[rt][u] = (f32x4){0.f, 0.f, 0.f, 0.f};

    float e2r[4];
    s16x8 b0[4][2], b1[4][2];

    const int wu = __builtin_amdgcn_readfirstlane(w);
    const unsigned short* ebase = escr + (size_t)wu * 49152 + lane * 8;

    load_b2(ebase, b0);                          // step 0

#pragma unroll 1
    for (int it = 0; it < 32; ++it) {
        const int s0 = it * 2, s1 = s0 + 1, s2 = s0 + 2;
        load_b2(ebase + boff(s1), b1);
        proc2(As, e2g, s0, wu, lane, n, b0, acc, e2r, bv, bv2, pk);
        if (it < 31) load_b2(ebase + boff(s2), b0);
        proc2(As, e2g, s1, wu, lane, n, b1, acc, e2r, bv, bv2, pk);
    }

    // butterfly over 16 lanes: exact (v1,v2) merge; ties flag via v2==v1
#pragma unroll
    for (int mask = 1; mask < 16; mask <<= 1) {
#pragma unroll
        for (int k = 0; k < 8; ++k) {
            const unsigned int opack = (unsigned int)__shfl_xor((int)pk[k], mask);
#pragma unroll
            for (int h = 0; h < 2; ++h) {
                const int slot = 2 * k + h;
                const int sh = h * 16;
                const float ov1 = __shfl_xor(bv[slot], mask);
                const float ov2 = __shfl_xor(bv2[slot], mask);
                if (ov1 < bv[slot]) {
                    bv2[slot] = fminf(bv[slot], ov2);   // bv2_self >= bv_self, drop it
                    bv[slot] = ov1;
                    pk[k] = (pk[k] & ~(0xFFFFu << sh)) | (opack & (0xFFFFu << sh));
                } else {
                    bv2[slot] = fminf(bv2[slot], ov1);  // ov2 >= ov1, drop it
                }
            }
        }
    }
    if (n == 0) {
#pragma unroll
        for (int rt = 0; rt < 4; ++rt)
#pragma unroll
            for (int r = 0; r < 4; ++r) {
                const int rl = rt * 16 + quad * 4 + r;   // C/D: row=quad*4+reg
                const int slot = rt * 4 + r;
                redv1[rl][w] = bv[slot];
                redv2[rl][w] = bv2[slot];
                redi[rl][w]  = (int)((pk[slot >> 1] >> ((slot & 1) * 16)) & 0xFFFFu);
            }
    }
    __syncthreads();
    if (t < 64) {
        float v1 = redv1[t][0];
        float v2 = redv2[t][0];
        int   bi = redi[t][0];
#pragma unroll
        for (int j = 1; j < 8; ++j) {
            const float o1 = redv1[t][j];
            const float o2 = redv2[t][j];
            const int   oi = redi[t][j];
            if (o1 < v1) { v2 = fminf(v1, o2); v1 = o1; bi = oi; }
            else         { v2 = fminf(v2, o1); }
        }
        bk_lds[t] = bi;
        out[(size_t)N_TOK * D_DIM + (size_t)(row0 + t)] = (float)bi;
        if (v2 - v1 <= THR_AMBIG) {              // true final gap (exact v2)
            const int pos = atomicAdd(cnt, 1);   // <= one per row
            list[pos] = row0 + t;
        }
    }
    __syncthreads();

    // ---- fused output tail (fixb corrects flagged rows later) ----
    float* zq = out;
    float* oh = out + (size_t)N_TOK * D_DIM + N_TOK;

#pragma unroll 1
    for (int rr = 0; rr < 8; ++rr) {            // z_q: wave w owns rows w*8..w*8+7
        const int rl  = w * 8 + rr;
        const int row = row0 + rl;
        const int bk  = bk_lds[rl] & (K_CODE - 1);
        f32x4 v = *(const f32x4*)&embed[(size_t)bk * D_DIM + lane * 4];
        __builtin_nontemporal_store(v, (f32x4*)&zq[(size_t)row * D_DIM + lane * 4]);
    }
    if (row0 < OH_SAFE_ROWS) {                  // scratch-overlap rows deferred
#pragma unroll 1
        for (int rr = 0; rr < 8; ++rr) {
            const int rl  = w * 8 + rr;
            const int row = row0 + rl;
            const int bk  = bk_lds[rl];
            float* ohrow = &oh[(size_t)row * K_CODE];
#pragma unroll
            for (int g = 0; g < 16; ++g) {
                const int base = (g * 64 + lane) * 4;
                f32x4 u;
                u.x = (bk == base    ) ? 1.0f : 0.0f;
                u.y = (bk == base + 1) ? 1.0f : 0.0f;
                u.z = (bk == base + 2) ? 1.0f : 0.0f;
                u.w = (bk == base + 3) ? 1.0f : 0.0f;
                __builtin_nontemporal_store(u, (f32x4*)&ohrow[base]);
            }
        }
    }
}

// ---------------------------------------------------------------------------
// Fixup A: exact 6-product recompute for listed rows (bit-identical to r12's
// chain; validated end-to-end in r15). Grid 16 = 8 code-slices x 2 chunk
// strides; each block gathers <=64 rows, sweeps its 512-code slice,
// atomicMin's a lex-packed u64 per row.
// ---------------------------------------------------------------------------
__global__ __launch_bounds__(512, 2)
void vq_fixa(const float* __restrict__ z_e, float* __restrict__ out) {
    __shared__ __align__(16) short As[49152];   // 96KB, r12 3-plane layout
    __shared__ float redv[64][9];
    __shared__ int   redi[64][9];
    __shared__ int   rows_lds[64];

    const unsigned short* escr = (const unsigned short*)(out + SCR_OFF);
    const float* e2g = out + E2_OFF;
    const int* list = (const int*)(out + LIST_OFF);
    unsigned long long* amin = (unsigned long long*)(out + AMIN_OFF);
    const int cntv = ((const int*)(out + CNT_OFF))[0];
    const int ncap = cntv < N_TOK ? cntv : N_TOK;
    if (ncap <= 0) return;

    const int t    = threadIdx.x;
    const int w    = t >> 6;
    const int lane = t & 63;
    const int n    = lane & 15;
    const int quad = lane >> 4;
    const int slice = blockIdx.x & 7;            // ktp 0..7 (512 codes each)
    const int c0    = blockIdx.x >> 3;

    const int wu = __builtin_amdgcn_readfirstlane(w);
    const unsigned short* ebase = escr + (size_t)wu * 49152 + lane * 8;

#pragma unroll 1
    for (int chunk = c0; chunk * 64 < ncap; chunk += 2) {
        const int nrows = (ncap - chunk * 64) < 64 ? (ncap - chunk * 64) : 64;
        if (t < 64) {
            const int j = chunk * 64 + t;
            rows_lds[t] = list[j < ncap ? j : chunk * 64];   // pad = dup row
        }
        __syncthreads();

        // gather-stage + convert A (3 planes, 64 rows)
#pragma unroll
        for (int i = 0; i < 4; ++i) {
            const int run  = t + 512 * i;
            const int qs   = run & 3;
            const int dcs  = (run >> 2) & 7;
            const int row  = run >> 5;
            const int grow = rows_lds[row];
            const float* src = z_e + (size_t)grow * D_DIM + dcs * 32 + qs * 8;
            float x[8];
            *(float4*)(x)     = *(const float4*)(src);
            *(float4*)(x + 4) = *(const float4*)(src + 4);
            s16x8 hv, mv, lv;
#pragma unroll
            for (int j = 0; j < 8; ++j) {
                const float xx = x[j];
                const unsigned short bh = f2bf(xx);
                const float r1 = xx - bf2f(bh);
                const unsigned short bm = f2bf(r1);
                hv[j] = (short)bh; mv[j] = (short)bm; lv[j] = (short)f2bf(r1 - bf2f(bm));
            }
            const int rt = row >> 4;
            const int ls = qs * 16 + (row & 15);
            *(s16x8*)&As[((0 * 4 + rt) * 8 + dcs) * 512 + ls * 8] = hv;
            *(s16x8*)&As[((1 * 4 + rt) * 8 + dcs) * 512 + ls * 8] = mv;
            *(s16x8*)&As[((2 * 4 + rt) * 8 + dcs) * 512 + ls * 8] = lv;
        }
        __syncthreads();

        float bv[16]; int bidx[16];
#pragma unroll
        for (int s = 0; s < 16; ++s) { bv[s] = 3.0e38f; bidx[s] = 0x7fffffff; }
        f32x4 acc[4][4];
#pragma unroll
        for (int rt = 0; rt < 4; ++rt)
#pragma unroll
            for (int u = 0; u < 4; ++u) acc[rt][u] = (f32x4){0.f, 0.f, 0.f, 0.f};
        float e2r[4];

#pragma unroll 1
        for (int dc = 0; dc < 8; ++dc) {         // single-buffered: tiny sweep
            s16x8 B[4][3];
            const unsigned short* p = ebase + (size_t)slice * 393216 + (size_t)dc * 1536;
#pragma unroll
            for (int u = 0; u < 4; ++u)
#pragma unroll
                for (int c = 0; c < 3; ++c)
                    B[u][c] = *(const s16x8*)(p + u * 12288 + c * 512);
            if (dc == 0) {
#pragma unroll
                for (int u = 0; u < 4; ++u)
                    e2r[u] = e2g[slice * 512 + (wu * 4 + u) * 16 + n];
            }
#pragma unroll
            for (int rt = 0; rt < 4; ++rt) {
                s16x8 af0 = *(const s16x8*)&As[((0 * 4 + rt) * 8 + dc) * 512 + lane * 8];
                s16x8 af1 = *(const s16x8*)&As[((1 * 4 + rt) * 8 + dc) * 512 + lane * 8];
                s16x8 af2 = *(const s16x8*)&As[((2 * 4 + rt) * 8 + dc) * 512 + lane * 8];
#pragma unroll
                for (int u = 0; u < 4; ++u) {
                    f32x4 a = acc[rt][u];
                    a = MFMA(af0, B[u][0], a);   // hh
                    a = MFMA(af0, B[u][1], a);   // hm
                    a = MFMA(af1, B[u][0], a);   // mh
                    a = MFMA(af1, B[u][1], a);   // mm
                    a = MFMA(af0, B[u][2], a);   // hl
                    a = MFMA(af2, B[u][0], a);   // lh
                    acc[rt][u] = a;
                }
            }
        }
#pragma unroll
        for (int u = 0; u < 4; ++u) {
            const int code = slice * 512 + (wu * 4 + u) * 16 + n;
#pragma unroll
            for (int rt = 0; rt < 4; ++rt)
#pragma unroll
                for (int r = 0; r < 4; ++r) {
                    const float val = fmaf(-2.0f, acc[rt][u][r], e2r[u]);
                    const int slot = rt * 4 + r;
                    if (val < bv[slot] || (val == bv[slot] && code < bidx[slot])) {
                        bv[slot] = val; bidx[slot] = code;
                    }
                }
        }
#pragma unroll
        for (int slot = 0; slot < 16; ++slot) {
#pragma unroll
            for (int mask = 1; mask < 16; mask <<= 1) {
                const float ov = __shfl_xor(bv[slot], mask);
                const int   oi = __shfl_xor(bidx[slot], mask);
                if (ov < bv[slot] || (ov == bv[slot] && oi < bidx[slot])) {
                    bv[slot] = ov; bidx[slot] = oi;
                }
            }
        }
        if (n == 0) {
#pragma unroll
            for (int rt = 0; rt < 4; ++rt)
#pragma unroll
                for (int r = 0; r < 4; ++r) {
                    const int rl = rt * 16 + quad * 4 + r;
                    redv[rl][w] = bv[rt * 4 + r];
                    redi[rl][w] = bidx[rt * 4 + r];
                }
        }
        __syncthreads();
        if (t < nrows) {
            float v = redv[t][0]; int bi = redi[t][0];
#pragma unroll
            for (int j = 1; j < 8; ++j) {
                const float v2 = redv[t][j]; const int i2 = redi[t][j];
                if (v2 < v || (v2 == v && i2 < bi)) { v = v2; bi = i2; }
            }
            atomicMin(&amin[chunk * 64 + t], packvi(v, bi));
        }
        __syncthreads();
    }
}

// ---------------------------------------------------------------------------
// Fixup B: apply corrected winners (idx, z_q row, one_hot 2-entry flip).
// ---------------------------------------------------------------------------
__global__ __launch_bounds__(256) void vq_fixb(const float* __restrict__ embed,
                                               float* __restrict__ out) {
    const int* list = (const int*)(out + LIST_OFF);
    const unsigned long long* amin = (const unsigned long long*)(out + AMIN_OFF);
    const int cntv = ((const int*)(out + CNT_OFF))[0];
    const int ncap = cntv < N_TOK ? cntv : N_TOK;

    float* idxf = out + (size_t)N_TOK * D_DIM;
    float* zq   = out;
    float* oh   = out + (size_t)N_TOK * D_DIM + N_TOK;
    const int t = threadIdx.x;

#pragma unroll 1
    for (int e = blockIdx.x; e < ncap; e += 32) {
        const int row = list[e];
        const int bi  = (int)(amin[e] & 0xffffffffu) & (K_CODE - 1);
        const int io  = ((int)idxf[row]) & (K_CODE - 1);
        if (bi != io) {
            if (t == 0) idxf[row] = (float)bi;
            if (t < 64) {
                f32x4 v = *(const f32x4*)&embed[(size_t)bi * D_DIM + t * 4];
                *(f32x4*)&zq[(size_t)row * D_DIM + t * 4] = v;
            }
            if (row < OH_SAFE_ROWS && t == 0) {
                oh[(size_t)row * K_CODE + io] = 0.0f;
                oh[(size_t)row * K_CODE + bi] = 1.0f;
            }
        }
    }
}

// ---------------------------------------------------------------------------
// Cleanup: one_hot for rows 32320..32767 (scratch overlap region). Runs last,
// reads final (fixed) idx.
// ---------------------------------------------------------------------------
__launch_bounds__(256, 8)
__global__ void vq_oh_tail(float* __restrict__ out) {
    __shared__ int bks[16];
    const int t    = threadIdx.x;
    const int w    = t >> 6;
    const int lane = t & 63;
    const int row0 = OH_SAFE_ROWS + blockIdx.x * 16;

    const float* idxf = out + (size_t)N_TOK * D_DIM;
    float* oh = out + (size_t)N_TOK * D_DIM + N_TOK;

    if (t < 16) bks[t] = ((int)idxf[row0 + t]) & (K_CODE - 1);
    __syncthreads();

#pragma unroll 1
    for (int rr = 0; rr < 4; ++rr) {
        const int r   = rr * 4 + w;
        const int row = row0 + r;
        const int bk  = bks[r];
        float* ohrow = &oh[(size_t)row * K_CODE];
#pragma unroll
        for (int g = 0; g < 16; ++g) {
            const int base = (g * 64 + lane) * 4;
            f32x4 u;
            u.x = (bk == base    ) ? 1.0f : 0.0f;
            u.y = (bk == base + 1) ? 1.0f : 0.0f;
            u.z = (bk == base + 2) ? 1.0f : 0.0f;
            u.w = (bk == base + 3) ? 1.0f : 0.0f;
            __builtin_nontemporal_store(u, (f32x4*)&ohrow[base]);
        }
    }
}

extern "C" void kernel_launch(void* const* d_in, const int* in_sizes, int n_in,
                              void* d_out, int out_size, void* d_ws, size_t ws_size,
                              hipStream_t stream) {
    const float* z_e   = (const float*)d_in[0];
    const float* embed = (const float*)d_in[1];
    float* out = (float*)d_out;

    hipLaunchKernelGGL(vq_prep,    dim3(K_CODE / 8), dim3(256), 0, stream, embed, out);
    hipLaunchKernelGGL(vq_pass1,   dim3(N_TOK / BM), dim3(512), 0, stream, z_e, embed, out);
    hipLaunchKernelGGL(vq_fixa,    dim3(16),  dim3(512), 0, stream, z_e, out);
    hipLaunchKernelGGL(vq_fixb,    dim3(32),  dim3(256), 0, stream, embed, out);
    hipLaunchKernelGGL(vq_oh_tail, dim3((N_TOK - OH_SAFE_ROWS) / 16), dim3(256), 0, stream, out);
}

// Round 11
// 827.394 us; speedup vs baseline: 10.0574x; 1.0851x over previous
//
#include <hip/hip_runtime.h>

// VQ-VAE quantization: N=32768, K=4096, D=256, fp32.
// Outputs (concat float32): z_q [N*D], idx [N] (as float), one_hot [N*K].
//
// Round-17: r16 (2-plane pass + exact-v2 flag + exact fixup) with fixa
// re-parallelized. r16 accounting: pass1 ~300us (per-byte model held; dropped
// out of rocprof top-5), but fixa ~130us -- 16 blocks re-streaming a 786KB
// B-slice per 64-row chunk on 16 CUs. Now: 128 blocks = 32 slices (128 codes)
// x 4 chunk-strides; u=1 per wave (no per-thread merge), B-slice 196KB,
// ~3 chunks/block, same 6-product chain => bit-identical exact winners.

#define N_TOK 32768
#define K_CODE 4096
#define D_DIM 256
#define BM 64
#define THR_AMBIG 0.125f
#define FIX_NSLICE 32
#define FIX_STRIDES 4

typedef float f32x4 __attribute__((ext_vector_type(4)));
typedef short s16x8 __attribute__((ext_vector_type(8)));

// scratch in out[] tail (floats): escr ushort[3*K*D] (=1,572,864 f), e2[K],
// list int[32768], amin u64[32768] (=65,536 f), cnt pad[64].
#define OUT_FLOATS 142639104u          // N*D + N + N*K
#define EFRAG_SHORTS (3u * K_CODE * D_DIM)
#define SCR_FLOATS (EFRAG_SHORTS / 2 + K_CODE + 32768u + 65536u + 64u) // 1,675,328
#define SCR_OFF    (OUT_FLOATS - SCR_FLOATS)         // starts in one_hot row 32359
#define E2_OFF     (SCR_OFF + EFRAG_SHORTS / 2)
#define LIST_OFF   (E2_OFF + K_CODE)
#define AMIN_OFF   (LIST_OFF + 32768u)
#define CNT_OFF    (AMIN_OFF + 65536u)
#define OH_SAFE_ROWS 32320             // rows >= this: one_hot deferred to vq_oh_tail

#define MFMA(a, b, c) __builtin_amdgcn_mfma_f32_16x16x32_bf16((a), (b), (c), 0, 0, 0)

static __device__ __forceinline__ unsigned short f2bf(float f) {
    unsigned int u = __float_as_uint(f);
    u = (u + 0x7fffu + ((u >> 16) & 1u)) >> 16;
    return (unsigned short)u;
}
static __device__ __forceinline__ float bf2f(unsigned short b) {
    return __uint_as_float(((unsigned int)b) << 16);
}
static __device__ __forceinline__ unsigned long long packvi(float v, int code) {
    unsigned int u = __float_as_uint(v);
    u = (u & 0x80000000u) ? ~u : (u ^ 0x80000000u);   // order-preserving map
    return ((unsigned long long)u << 32) | (unsigned int)code;
}

// ---------------------------------------------------------------------------
// Prep: embed -> fragment-ordered bf16 h/m/l planes + e2; init list/amin/cnt.
// Frag layout (1KB): [ct_g(256)][dc(8)][c(3)][lane(64)][8 bf16].
// ---------------------------------------------------------------------------
__global__ __launch_bounds__(256) void vq_prep(const float* __restrict__ embed,
                                               float* __restrict__ out) {
    __shared__ float part[8][33];
    unsigned short* escr = (unsigned short*)(out + SCR_OFF);
    float* e2g = out + E2_OFF;

    const int t    = threadIdx.x;
    const int cl   = t >> 5;
    const int r32  = t & 31;
    const int dc   = r32 >> 2;
    const int quad = r32 & 3;
    const int k    = blockIdx.x * 8 + cl;

    if (blockIdx.x == 0) {                      // re-init fixup state every launch
        if (t == 0) ((int*)(out + CNT_OFF))[0] = 0;
        unsigned long long* am = (unsigned long long*)(out + AMIN_OFF);
        for (int i = t; i < 32768; i += 256) am[i] = ~0ull;
    }

    const float* src = embed + (size_t)k * D_DIM + dc * 32 + quad * 8;
    float x[8];
    *(float4*)(x)     = *(const float4*)(src);
    *(float4*)(x + 4) = *(const float4*)(src + 4);

    s16x8 hv, mv, lv;
    float s2 = 0.0f;
#pragma unroll
    for (int j = 0; j < 8; ++j) {
        const float xx = x[j];
        s2 += xx * xx;
        const unsigned short bh = f2bf(xx);
        const float r1 = xx - bf2f(bh);
        const unsigned short bm = f2bf(r1);
        hv[j] = (short)bh; mv[j] = (short)bm; lv[j] = (short)f2bf(r1 - bf2f(bm));
    }

    const int ct_g = k >> 4;
    const int lane = quad * 16 + (k & 15);
    const size_t base = ((size_t)(ct_g * 8 + dc) * 3) * 512 + lane * 8;
    *(s16x8*)&escr[base]        = hv;
    *(s16x8*)&escr[base + 512]  = mv;
    *(s16x8*)&escr[base + 1024] = lv;

    part[cl][r32] = s2;
    __syncthreads();
    if (t < 8) {
        float s = 0.0f;
#pragma unroll
        for (int j = 0; j < 32; ++j) s += part[t][j];   // fixed order: deterministic
        e2g[blockIdx.x * 8 + t] = s;
    }
}

// ---- helpers (2-plane main loop) ------------------------------------------
static __device__ __forceinline__ void load_b2(const unsigned short* __restrict__ p,
                                               s16x8 (&buf)[4][2]) {
#pragma unroll
    for (int u = 0; u < 4; ++u)
#pragma unroll
        for (int c = 0; c < 2; ++c)
            buf[u][c] = *(const s16x8*)(p + u * 12288 + c * 512);
}

static __device__ __forceinline__ size_t boff(int s) {
    return (size_t)(s >> 3) * 393216 + (size_t)(s & 7) * 1536;
}

static __device__ __forceinline__ void proc2(const short* As,
        const float* __restrict__ e2g, int s, int wu, int lane, int n,
        s16x8 (&B)[4][2], f32x4 (&acc)[4][4], float (&e2r)[4],
        float (&bv)[16], float (&bv2)[16], unsigned int (&pk)[8]) {
    const int ktp = s >> 3;
    const int dc  = s & 7;
    if (dc == 0) {       // prefetch e2 8 steps ahead of its dc==7 use
#pragma unroll
        for (int u = 0; u < 4; ++u)
            e2r[u] = e2g[ktp * 512 + (wu * 4 + u) * 16 + n];
    }
#pragma unroll
    for (int rt = 0; rt < 4; ++rt) {
        s16x8 af0 = *(const s16x8*)&As[((0 * 4 + rt) * 8 + dc) * 512 + lane * 8];
        s16x8 af1 = *(const s16x8*)&As[((1 * 4 + rt) * 8 + dc) * 512 + lane * 8];
#pragma unroll
        for (int u = 0; u < 4; ++u) {
            f32x4 a = acc[rt][u];
            a = MFMA(af0, B[u][0], a);           // hh
            a = MFMA(af0, B[u][1], a);           // hm
            a = MFMA(af1, B[u][0], a);           // mh
            a = MFMA(af1, B[u][1], a);           // mm  (prefix of the exact 6-chain)
            acc[rt][u] = a;
        }
    }
    if (dc == 7) {   // merge: (v1, v2) exact; codes ascend => first-occurrence
#pragma unroll
        for (int u = 0; u < 4; ++u) {
            const int code = ktp * 512 + (wu * 4 + u) * 16 + n;
#pragma unroll
            for (int rt = 0; rt < 4; ++rt)
#pragma unroll
                for (int r = 0; r < 4; ++r) {
                    const float val = fmaf(-2.0f, acc[rt][u][r], e2r[u]);
                    const int slot = rt * 4 + r;
                    const int k = slot >> 1, sh = (slot & 1) * 16;
                    if (val < bv[slot]) {
                        bv2[slot] = bv[slot];
                        bv[slot] = val;
                        pk[k] = (pk[k] & ~(0xFFFFu << sh)) | ((unsigned int)code << sh);
                    } else {
                        bv2[slot] = fminf(bv2[slot], val);
                    }
                }
        }
#pragma unroll
        for (int rt = 0; rt < 4; ++rt)
#pragma unroll
            for (int u = 0; u < 4; ++u) acc[rt][u] = (f32x4){0.f, 0.f, 0.f, 0.f};
    }
}

// ---------------------------------------------------------------------------
// Pass 1 (2-plane): 512 thr = 8 waves, 64 rows/block, grid 512. LDS = A h,m
// (64KB). 64-step (ktp,dc) loop, u=4/wave, ping-pong B. Per-slot (v1, v2,
// packed code); flag = final gap <= THR. Flagged rows -> list; outputs get the
// pass-1 winner (fixb corrects the few changed rows afterwards).
// ---------------------------------------------------------------------------
__global__ __launch_bounds__(512, 2)
void vq_pass1(const float* __restrict__ z_e,
              const float* __restrict__ embed,
              float* __restrict__ out) {
    __shared__ __align__(16) short As[32768];   // [(c*4+rt)*8+dc]*512 + ls*8, c in {h,m}
    __shared__ float redv1[64][9];
    __shared__ float redv2[64][9];
    __shared__ int   redi[64][9];
    __shared__ int   bk_lds[64];

    const unsigned short* escr = (const unsigned short*)(out + SCR_OFF);
    const float* e2g = out + E2_OFF;
    int* list = (int*)(out + LIST_OFF);
    int* cnt  = (int*)(out + CNT_OFF);

    const int t    = threadIdx.x;
    const int w    = t >> 6;
    const int lane = t & 63;
    const int n    = lane & 15;
    const int quad = lane >> 4;
    const int row0 = blockIdx.x * BM;

    // ---- stage + convert A (h,m planes) ----
#pragma unroll
    for (int i = 0; i < 4; ++i) {
        const int run  = t + 512 * i;           // (row, dcs, qs): 64*8*4 = 2048
        const int qs   = run & 3;
        const int dcs  = (run >> 2) & 7;
        const int row  = run >> 5;
        const float* src = z_e + (size_t)(row0 + row) * D_DIM + dcs * 32 + qs * 8;
        float x[8];
        *(float4*)(x)     = *(const float4*)(src);
        *(float4*)(x + 4) = *(const float4*)(src + 4);
        s16x8 hv, mv;
#pragma unroll
        for (int j = 0; j < 8; ++j) {
            const float xx = x[j];
            const unsigned short bh = f2bf(xx);
            hv[j] = (short)bh;
            mv[j] = (short)f2bf(xx - bf2f(bh));
        }
        const int rt = row >> 4;
        const int ls = qs * 16 + (row & 15);
        *(s16x8*)&As[((0 * 4 + rt) * 8 + dcs) * 512 + ls * 8] = hv;
        *(s16x8*)&As[((1 * 4 + rt) * 8 + dcs) * 512 + ls * 8] = mv;
    }
    __syncthreads();

    float bv[16], bv2[16];
    unsigned int pk[8];
#pragma unroll
    for (int s = 0; s < 16; ++s) { bv[s] = 3.0e38f; bv2[s] = 3.0e38f; }
#pragma unroll
    for (int k = 0; k < 8; ++k) pk[k] = 0u;

    f32x4 acc[4][4];
#pragma unroll
    for (int rt = 0; rt < 4; ++rt)
#pragma unroll
        for (int u = 0; u < 4; ++u) acc[rt][u] = (f32x4){0.f, 0.f, 0.f, 0.f};

    float e2r[4];
    s16x8 b0[4][2], b1[4][2];

    const int wu = __builtin_amdgcn_readfirstlane(w);
    const unsigned short* ebase = escr + (size_t)wu * 49152 + lane * 8;

    load_b2(ebase, b0);                          // step 0

#pragma unroll 1
    for (int it = 0; it < 32; ++it) {
        const int s0 = it * 2, s1 = s0 + 1, s2 = s0 + 2;
        load_b2(ebase + boff(s1), b1);
        proc2(As, e2g, s0, wu, lane, n, b0, acc, e2r, bv, bv2, pk);
        if (it < 31) load_b2(ebase + boff(s2), b0);
        proc2(As, e2g, s1, wu, lane, n, b1, acc, e2r, bv, bv2, pk);
    }

    // butterfly over 16 lanes: exact (v1,v2) merge; ties flag via v2==v1
#pragma unroll
    for (int mask = 1; mask < 16; mask <<= 1) {
#pragma unroll
        for (int k = 0; k < 8; ++k) {
            const unsigned int opack = (unsigned int)__shfl_xor((int)pk[k], mask);
#pragma unroll
            for (int h = 0; h < 2; ++h) {
                const int slot = 2 * k + h;
                const int sh = h * 16;
                const float ov1 = __shfl_xor(bv[slot], mask);
                const float ov2 = __shfl_xor(bv2[slot], mask);
                if (ov1 < bv[slot]) {
                    bv2[slot] = fminf(bv[slot], ov2);   // bv2_self >= bv_self, drop it
                    bv[slot] = ov1;
                    pk[k] = (pk[k] & ~(0xFFFFu << sh)) | (opack & (0xFFFFu << sh));
                } else {
                    bv2[slot] = fminf(bv2[slot], ov1);  // ov2 >= ov1, drop it
                }
            }
        }
    }
    if (n == 0) {
#pragma unroll
        for (int rt = 0; rt < 4; ++rt)
#pragma unroll
            for (int r = 0; r < 4; ++r) {
                const int rl = rt * 16 + quad * 4 + r;   // C/D: row=quad*4+reg
                const int slot = rt * 4 + r;
                redv1[rl][w] = bv[slot];
                redv2[rl][w] = bv2[slot];
                redi[rl][w]  = (int)((pk[slot >> 1] >> ((slot & 1) * 16)) & 0xFFFFu);
            }
    }
    __syncthreads();
    if (t < 64) {
        float v1 = redv1[t][0];
        float v2 = redv2[t][0];
        int   bi = redi[t][0];
#pragma unroll
        for (int j = 1; j < 8; ++j) {
            const float o1 = redv1[t][j];
            const float o2 = redv2[t][j];
            const int   oi = redi[t][j];
            if (o1 < v1) { v2 = fminf(v1, o2); v1 = o1; bi = oi; }
            else         { v2 = fminf(v2, o1); }
        }
        bk_lds[t] = bi;
        out[(size_t)N_TOK * D_DIM + (size_t)(row0 + t)] = (float)bi;
        if (v2 - v1 <= THR_AMBIG) {              // true final gap (exact v2)
            const int pos = atomicAdd(cnt, 1);   // <= one per row
            list[pos] = row0 + t;
        }
    }
    __syncthreads();

    // ---- fused output tail (fixb corrects flagged rows later) ----
    float* zq = out;
    float* oh = out + (size_t)N_TOK * D_DIM + N_TOK;

#pragma unroll 1
    for (int rr = 0; rr < 8; ++rr) {            // z_q: wave w owns rows w*8..w*8+7
        const int rl  = w * 8 + rr;
        const int row = row0 + rl;
        const int bk  = bk_lds[rl] & (K_CODE - 1);
        f32x4 v = *(const f32x4*)&embed[(size_t)bk * D_DIM + lane * 4];
        __builtin_nontemporal_store(v, (f32x4*)&zq[(size_t)row * D_DIM + lane * 4]);
    }
    if (row0 < OH_SAFE_ROWS) {                  // scratch-overlap rows deferred
#pragma unroll 1
        for (int rr = 0; rr < 8; ++rr) {
            const int rl  = w * 8 + rr;
            const int row = row0 + rl;
            const int bk  = bk_lds[rl];
            float* ohrow = &oh[(size_t)row * K_CODE];
#pragma unroll
            for (int g = 0; g < 16; ++g) {
                const int base = (g * 64 + lane) * 4;
                f32x4 u;
                u.x = (bk == base    ) ? 1.0f : 0.0f;
                u.y = (bk == base + 1) ? 1.0f : 0.0f;
                u.z = (bk == base + 2) ? 1.0f : 0.0f;
                u.w = (bk == base + 3) ? 1.0f : 0.0f;
                __builtin_nontemporal_store(u, (f32x4*)&ohrow[base]);
            }
        }
    }
}

// ---------------------------------------------------------------------------
// Fixup A: exact 6-product recompute for listed rows (bit-identical chain;
// validated end-to-end in r15). Grid 128 = 32 slices (128 codes) x 4 chunk
// strides; u=1/wave. Each block gathers <=64 rows, sweeps its 196KB slice,
// atomicMin's a lex-packed u64 per row.
// ---------------------------------------------------------------------------
__global__ __launch_bounds__(512, 2)
void vq_fixa(const float* __restrict__ z_e, float* __restrict__ out) {
    __shared__ __align__(16) short As[49152];   // 96KB, 3-plane layout
    __shared__ float redv[64][9];
    __shared__ int   redi[64][9];
    __shared__ int   rows_lds[64];

    const unsigned short* escr = (const unsigned short*)(out + SCR_OFF);
    const float* e2g = out + E2_OFF;
    const int* list = (const int*)(out + LIST_OFF);
    unsigned long long* amin = (unsigned long long*)(out + AMIN_OFF);
    const int cntv = ((const int*)(out + CNT_OFF))[0];
    const int ncap = cntv < N_TOK ? cntv : N_TOK;
    if (ncap <= 0) return;

    const int t    = threadIdx.x;
    const int w    = t >> 6;
    const int lane = t & 63;
    const int n    = lane & 15;
    const int quad = lane >> 4;
    const int slice = blockIdx.x & (FIX_NSLICE - 1);   // 128 codes each
    const int c0    = blockIdx.x / FIX_NSLICE;

    const int wu = __builtin_amdgcn_readfirstlane(w);
    // ct_g = slice*8 + wu; code = slice*128 + wu*16 + n (same for all slots)
    const unsigned short* ebase = escr + (size_t)(slice * 8 + wu) * 12288 + lane * 8;
    const int mycode = slice * 128 + wu * 16 + n;

#pragma unroll 1
    for (int chunk = c0; chunk * 64 < ncap; chunk += FIX_STRIDES) {
        const int nrows = (ncap - chunk * 64) < 64 ? (ncap - chunk * 64) : 64;
        if (t < 64) {
            const int j = chunk * 64 + t;
            rows_lds[t] = list[j < ncap ? j : chunk * 64];   // pad = dup row
        }
        __syncthreads();

        // gather-stage + convert A (3 planes, 64 rows)
#pragma unroll
        for (int i = 0; i < 4; ++i) {
            const int run  = t + 512 * i;
            const int qs   = run & 3;
            const int dcs  = (run >> 2) & 7;
            const int row  = run >> 5;
            const int grow = rows_lds[row];
            const float* src = z_e + (size_t)grow * D_DIM + dcs * 32 + qs * 8;
            float x[8];
            *(float4*)(x)     = *(const float4*)(src);
            *(float4*)(x + 4) = *(const float4*)(src + 4);
            s16x8 hv, mv, lv;
#pragma unroll
            for (int j = 0; j < 8; ++j) {
                const float xx = x[j];
                const unsigned short bh = f2bf(xx);
                const float r1 = xx - bf2f(bh);
                const unsigned short bm = f2bf(r1);
                hv[j] = (short)bh; mv[j] = (short)bm; lv[j] = (short)f2bf(r1 - bf2f(bm));
            }
            const int rt = row >> 4;
            const int ls = qs * 16 + (row & 15);
            *(s16x8*)&As[((0 * 4 + rt) * 8 + dcs) * 512 + ls * 8] = hv;
            *(s16x8*)&As[((1 * 4 + rt) * 8 + dcs) * 512 + ls * 8] = mv;
            *(s16x8*)&As[((2 * 4 + rt) * 8 + dcs) * 512 + ls * 8] = lv;
        }
        __syncthreads();

        f32x4 acc[4];
#pragma unroll
        for (int rt = 0; rt < 4; ++rt) acc[rt] = (f32x4){0.f, 0.f, 0.f, 0.f};
        float e2v = 0.0f;

#pragma unroll 1
        for (int dc = 0; dc < 8; ++dc) {         // single-buffered: tiny sweep
            s16x8 B[3];
            const unsigned short* p = ebase + (size_t)dc * 1536;
#pragma unroll
            for (int c = 0; c < 3; ++c)
                B[c] = *(const s16x8*)(p + c * 512);
            if (dc == 0) e2v = e2g[mycode];
#pragma unroll
            for (int rt = 0; rt < 4; ++rt) {
                s16x8 af0 = *(const s16x8*)&As[((0 * 4 + rt) * 8 + dc) * 512 + lane * 8];
                s16x8 af1 = *(const s16x8*)&As[((1 * 4 + rt) * 8 + dc) * 512 + lane * 8];
                s16x8 af2 = *(const s16x8*)&As[((2 * 4 + rt) * 8 + dc) * 512 + lane * 8];
                f32x4 a = acc[rt];
                a = MFMA(af0, B[0], a);          // hh
                a = MFMA(af0, B[1], a);          // hm
                a = MFMA(af1, B[0], a);          // mh
                a = MFMA(af1, B[1], a);          // mm
                a = MFMA(af0, B[2], a);          // hl
                a = MFMA(af2, B[0], a);          // lh
                acc[rt] = a;
            }
        }

        float bv[16]; int bidx[16];
#pragma unroll
        for (int rt = 0; rt < 4; ++rt)
#pragma unroll
            for (int r = 0; r < 4; ++r) {
                bv[rt * 4 + r]   = fmaf(-2.0f, acc[rt][r], e2v);
                bidx[rt * 4 + r] = mycode;
            }
#pragma unroll
        for (int slot = 0; slot < 16; ++slot) {
#pragma unroll
            for (int mask = 1; mask < 16; mask <<= 1) {
                const float ov = __shfl_xor(bv[slot], mask);
                const int   oi = __shfl_xor(bidx[slot], mask);
                if (ov < bv[slot] || (ov == bv[slot] && oi < bidx[slot])) {
                    bv[slot] = ov; bidx[slot] = oi;
                }
            }
        }
        if (n == 0) {
#pragma unroll
            for (int rt = 0; rt < 4; ++rt)
#pragma unroll
                for (int r = 0; r < 4; ++r) {
                    const int rl = rt * 16 + quad * 4 + r;
                    redv[rl][w] = bv[rt * 4 + r];
                    redi[rl][w] = bidx[rt * 4 + r];
                }
        }
        __syncthreads();
        if (t < nrows) {
            float v = redv[t][0]; int bi = redi[t][0];
#pragma unroll
            for (int j = 1; j < 8; ++j) {
                const float v2 = redv[t][j]; const int i2 = redi[t][j];
                if (v2 < v || (v2 == v && i2 < bi)) { v = v2; bi = i2; }
            }
            atomicMin(&amin[chunk * 64 + t], packvi(v, bi));
        }
        __syncthreads();
    }
}

// ---------------------------------------------------------------------------
// Fixup B: apply corrected winners (idx, z_q row, one_hot 2-entry flip).
// ---------------------------------------------------------------------------
__global__ __launch_bounds__(256) void vq_fixb(const float* __restrict__ embed,
                                               float* __restrict__ out) {
    const int* list = (const int*)(out + LIST_OFF);
    const unsigned long long* amin = (const unsigned long long*)(out + AMIN_OFF);
    const int cntv = ((const int*)(out + CNT_OFF))[0];
    const int ncap = cntv < N_TOK ? cntv : N_TOK;

    float* idxf = out + (size_t)N_TOK * D_DIM;
    float* zq   = out;
    float* oh   = out + (size_t)N_TOK * D_DIM + N_TOK;
    const int t = threadIdx.x;

#pragma unroll 1
    for (int e = blockIdx.x; e < ncap; e += 32) {
        const int row = list[e];
        const int bi  = (int)(amin[e] & 0xffffffffu) & (K_CODE - 1);
        const int io  = ((int)idxf[row]) & (K_CODE - 1);
        if (bi != io) {
            if (t == 0) idxf[row] = (float)bi;
            if (t < 64) {
                f32x4 v = *(const f32x4*)&embed[(size_t)bi * D_DIM + t * 4];
                *(f32x4*)&zq[(size_t)row * D_DIM + t * 4] = v;
            }
            if (row < OH_SAFE_ROWS && t == 0) {
                oh[(size_t)row * K_CODE + io] = 0.0f;
                oh[(size_t)row * K_CODE + bi] = 1.0f;
            }
        }
    }
}

// ---------------------------------------------------------------------------
// Cleanup: one_hot for rows 32320..32767 (scratch overlap region). Runs last,
// reads final (fixed) idx.
// ---------------------------------------------------------------------------
__launch_bounds__(256, 8)
__global__ void vq_oh_tail(float* __restrict__ out) {
    __shared__ int bks[16];
    const int t    = threadIdx.x;
    const int w    = t >> 6;
    const int lane = t & 63;
    const int row0 = OH_SAFE_ROWS + blockIdx.x * 16;

    const float* idxf = out + (size_t)N_TOK * D_DIM;
    float* oh = out + (size_t)N_TOK * D_DIM + N_TOK;

    if (t < 16) bks[t] = ((int)idxf[row0 + t]) & (K_CODE - 1);
    __syncthreads();

#pragma unroll 1
    for (int rr = 0; rr < 4; ++rr) {
        const int r   = rr * 4 + w;
        const int row = row0 + r;
        const int bk  = bks[r];
        float* ohrow = &oh[(size_t)row * K_CODE];
#pragma unroll
        for (int g = 0; g < 16; ++g) {
            const int base = (g * 64 + lane) * 4;
            f32x4 u;
            u.x = (bk == base    ) ? 1.0f : 0.0f;
            u.y = (bk == base + 1) ? 1.0f : 0.0f;
            u.z = (bk == base + 2) ? 1.0f : 0.0f;
            u.w = (bk == base + 3) ? 1.0f : 0.0f;
            __builtin_nontemporal_store(u, (f32x4*)&ohrow[base]);
        }
    }
}

extern "C" void kernel_launch(void* const* d_in, const int* in_sizes, int n_in,
                              void* d_out, int out_size, void* d_ws, size_t ws_size,
                              hipStream_t stream) {
    const float* z_e   = (const float*)d_in[0];
    const float* embed = (const float*)d_in[1];
    float* out = (float*)d_out;

    hipLaunchKernelGGL(vq_prep,    dim3(K_CODE / 8), dim3(256), 0, stream, embed, out);
    hipLaunchKernelGGL(vq_pass1,   dim3(N_TOK / BM), dim3(512), 0, stream, z_e, embed, out);
    hipLaunchKernelGGL(vq_fixa,    dim3(FIX_NSLICE * FIX_STRIDES), dim3(512), 0, stream, z_e, out);
    hipLaunchKernelGGL(vq_fixb,    dim3(32),  dim3(256), 0, stream, embed, out);
    hipLaunchKernelGGL(vq_oh_tail, dim3((N_TOK - OH_SAFE_ROWS) / 16), dim3(256), 0, stream, out);
}